// Round 1
// baseline (1855.665 us; speedup 1.0000x reference)
//
#include <hip/hip_runtime.h>
#include <math.h>

#define N_NODES 50000
#define N_EDGES 800000

// ---------------------------------------------------------------------------
// Generic tiled GEMM:  C[M x N] = op(A[M x K] @ W[N x K]^T + bias)
// 64x64 tile, 256 threads, 4x4 micro-tile, K-step 16.
// ---------------------------------------------------------------------------
template<bool RELU, bool BIAS>
__global__ __launch_bounds__(256, 4)
void gemm_nt(const float* __restrict__ A, int lda,
             const float* __restrict__ W, int ldw,
             const float* __restrict__ bias,
             float* __restrict__ C, int ldc,
             int M, int N, int K)
{
    __shared__ float As[16][68];
    __shared__ float Ws[16][68];
    const int tid = threadIdx.x;
    const int tx = tid & 15, ty = tid >> 4;
    const int m0 = blockIdx.x * 64;
    const int n0 = blockIdx.y * 64;

    float bv[4];
#pragma unroll
    for (int j = 0; j < 4; ++j) {
        int n = n0 + tx * 4 + j;
        bv[j] = (BIAS && n < N) ? bias[n] : 0.f;
    }
    float acc[4][4];
#pragma unroll
    for (int i = 0; i < 4; ++i)
#pragma unroll
        for (int j = 0; j < 4; ++j) acc[i][j] = bv[j];

    const int kk = tid & 15;   // k within panel
    const int rg = tid >> 4;   // row group 0..15
    const int ksteps = (K + 15) >> 4;
    for (int kp = 0; kp < ksteps; ++kp) {
        const int k0 = kp * 16;
        const int k = k0 + kk;
        __syncthreads();
#pragma unroll
        for (int j = 0; j < 4; ++j) {
            int m = m0 + rg * 4 + j;
            As[kk][rg * 4 + j] = (m < M && k < K) ? A[(size_t)m * lda + k] : 0.f;
            int n = n0 + rg * 4 + j;
            Ws[kk][rg * 4 + j] = (n < N && k < K) ? W[(size_t)n * ldw + k] : 0.f;
        }
        __syncthreads();
#pragma unroll
        for (int q = 0; q < 16; ++q) {
            float4 a = *(const float4*)&As[q][ty * 4];
            float4 w = *(const float4*)&Ws[q][tx * 4];
            float av[4] = {a.x, a.y, a.z, a.w};
#pragma unroll
            for (int i = 0; i < 4; ++i) {
                acc[i][0] += av[i] * w.x;
                acc[i][1] += av[i] * w.y;
                acc[i][2] += av[i] * w.z;
                acc[i][3] += av[i] * w.w;
            }
        }
    }
#pragma unroll
    for (int i = 0; i < 4; ++i) {
        int m = m0 + ty * 4 + i;
        if (m >= M) continue;
        int n = n0 + tx * 4;
        if (n + 4 <= N) {
            float4 v;
            v.x = acc[i][0]; v.y = acc[i][1]; v.z = acc[i][2]; v.w = acc[i][3];
            if (RELU) {
                v.x = fmaxf(v.x, 0.f); v.y = fmaxf(v.y, 0.f);
                v.z = fmaxf(v.z, 0.f); v.w = fmaxf(v.w, 0.f);
            }
            *(float4*)&C[(size_t)m * ldc + n] = v;
        } else {
#pragma unroll
            for (int j = 0; j < 4; ++j) {
                if (n + j < N) {
                    float v = acc[i][j];
                    if (RELU) v = fmaxf(v, 0.f);
                    C[(size_t)m * ldc + n + j] = v;
                }
            }
        }
    }
}

// ---------------------------------------------------------------------------
// GLX[n][g] = LF[n] @ gate_w1[:,128:256]^T  (already done)  += node_extra part + gate_b1
// ---------------------------------------------------------------------------
__global__ void fix_glx(float* __restrict__ GLX, const float* __restrict__ ne,
                        const float* __restrict__ gw1, const float* __restrict__ gb1)
{
    int idx = blockIdx.x * 256 + threadIdx.x;
    if (idx >= N_NODES * 32) return;
    int n = idx >> 5, g = idx & 31;
    GLX[idx] += ne[n * 2] * gw1[(size_t)g * 386 + 384]
              + ne[n * 2 + 1] * gw1[(size_t)g * 386 + 385] + gb1[g];
}

// ---------------------------------------------------------------------------
// Fused edge kernel: 64 edges per block, 256 threads.
//   t       = h_edge @ bond_w^T + Lp[el] + Rp[er]
//   is      = inter_w2 . relu(inter_w1 @ t + ib1) + ib2
//   g       = sigmoid(gate_w2 . relu(gate_w1e @ h_edge + GLX[el] + GR[er]) + gb2)
//   force   = is*g * rel_vec * 5 / ((d+1e-6)(d+5))
//   atomicAdd into dp[el]
// Gate GEMM fused into GEMM1's k-loop (shares the sA reads).
// ---------------------------------------------------------------------------
__global__ __launch_bounds__(256, 2)
void edge_kernel(const float* __restrict__ h_edge,
                 const int*   __restrict__ eidx,
                 const float* __restrict__ rel_vec,
                 const float* __restrict__ dist,
                 const float* __restrict__ Lp,
                 const float* __restrict__ Rp,
                 const float* __restrict__ GLX,
                 const float* __restrict__ GR,
                 const float* __restrict__ bond_w,
                 const float* __restrict__ iw1,
                 const float* __restrict__ ib1,
                 const float* __restrict__ iw2,
                 const float* __restrict__ ib2,
                 const float* __restrict__ gw1,
                 const float* __restrict__ gw2,
                 const float* __restrict__ gb2,
                 float* __restrict__ dp)
{
    __shared__ float sA[64][132];   // h_edge tile [e][k], later t tile
    __shared__ float sW[16][132];   // weight k-panel [k][n]
    __shared__ float sWg[16][34];   // gate weight k-panel [k][g]
    __shared__ int   sEL[64], sER[64];
    __shared__ float sG[64], sIS[64];

    const int tid = threadIdx.x;
    const int tx = tid & 15, ty = tid >> 4;
    const int eb = blockIdx.x * 64;
    const int e0 = ty * 4;     // 4 edges per thread
    const int o0 = tx * 8;     // 8 outputs per thread
    const int g0 = tx * 2;     // 2 gate outputs per thread

    if (tid < 64) {
        sEL[tid] = eidx[eb + tid];
        sER[tid] = eidx[N_EDGES + eb + tid];
    }
    // stage h_edge tile (coalesced float4 global, contiguous b128 LDS writes)
#pragma unroll
    for (int j = 0; j < 8; ++j) {
        int fid = j * 256 + tid;          // 0..2047 float4s
        int e = fid >> 5;
        int kq = (fid & 31) << 2;
        float4 v = *(const float4*)&h_edge[(size_t)(eb + e) * 128 + kq];
        *(float4*)&sA[e][kq] = v;
    }

    float acc[4][8];
    float accg[4][2];
#pragma unroll
    for (int i = 0; i < 4; ++i) {
#pragma unroll
        for (int j = 0; j < 8; ++j) acc[i][j] = 0.f;
        accg[i][0] = 0.f; accg[i][1] = 0.f;
    }

    const int kk = tid & 15;
    const int ng = tid >> 4;

    // ---- GEMM1 (bond) + fused gate GEMM ----
    for (int kp = 0; kp < 8; ++kp) {
        const int k0 = kp * 16;
        __syncthreads();
#pragma unroll
        for (int j = 0; j < 8; ++j) {
            int n = ng * 8 + j;
            sW[kk][n] = bond_w[(size_t)n * 128 + k0 + kk];
        }
#pragma unroll
        for (int j = 0; j < 2; ++j) {
            int g = ng * 2 + j;
            sWg[kk][g] = gw1[(size_t)g * 386 + k0 + kk];
        }
        __syncthreads();
#pragma unroll
        for (int q = 0; q < 16; ++q) {
            const int k = k0 + q;
            float a[4];
            a[0] = sA[e0 + 0][k]; a[1] = sA[e0 + 1][k];
            a[2] = sA[e0 + 2][k]; a[3] = sA[e0 + 3][k];
            float4 wA = *(const float4*)&sW[q][o0];
            float4 wB = *(const float4*)&sW[q][o0 + 4];
            float2 wg = *(const float2*)&sWg[q][g0];
#pragma unroll
            for (int i = 0; i < 4; ++i) {
                acc[i][0] += a[i] * wA.x; acc[i][1] += a[i] * wA.y;
                acc[i][2] += a[i] * wA.z; acc[i][3] += a[i] * wA.w;
                acc[i][4] += a[i] * wB.x; acc[i][5] += a[i] * wB.y;
                acc[i][6] += a[i] * wB.z; acc[i][7] += a[i] * wB.w;
                accg[i][0] += a[i] * wg.x;
                accg[i][1] += a[i] * wg.y;
            }
        }
    }

    // ---- gate epilogue: + GLX[el] + GR[er], relu, dot gate_w2, reduce, sigmoid ----
    {
        float gw2a = gw2[g0], gw2b = gw2[g0 + 1];
        float gbias2 = gb2[0];
#pragma unroll
        for (int i = 0; i < 4; ++i) {
            int le = sEL[e0 + i], re = sER[e0 + i];
            float2 gl = *(const float2*)&GLX[(size_t)le * 32 + g0];
            float2 gr = *(const float2*)&GR[(size_t)re * 32 + g0];
            float p = fmaxf(accg[i][0] + gl.x + gr.x, 0.f) * gw2a
                    + fmaxf(accg[i][1] + gl.y + gr.y, 0.f) * gw2b;
            p += __shfl_xor(p, 1);
            p += __shfl_xor(p, 2);
            p += __shfl_xor(p, 4);
            p += __shfl_xor(p, 8);
            if (tx == 0) sG[e0 + i] = 1.f / (1.f + expf(-(p + gbias2)));
        }
    }

    __syncthreads();   // all sA/sWg reads of GEMM1 done

    // ---- t = acc + Lp[el] + Rp[er]  -> overwrite sA ----
#pragma unroll
    for (int i = 0; i < 4; ++i) {
        int le = sEL[e0 + i], re = sER[e0 + i];
        const float4* lp = (const float4*)&Lp[(size_t)le * 128 + o0];
        const float4* rp = (const float4*)&Rp[(size_t)re * 128 + o0];
        float4 l0 = lp[0], l1 = lp[1], r0 = rp[0], r1 = rp[1];
        float4 t0, t1;
        t0.x = acc[i][0] + l0.x + r0.x; t0.y = acc[i][1] + l0.y + r0.y;
        t0.z = acc[i][2] + l0.z + r0.z; t0.w = acc[i][3] + l0.w + r0.w;
        t1.x = acc[i][4] + l1.x + r1.x; t1.y = acc[i][5] + l1.y + r1.y;
        t1.z = acc[i][6] + l1.z + r1.z; t1.w = acc[i][7] + l1.w + r1.w;
        *(float4*)&sA[e0 + i][o0] = t0;
        *(float4*)&sA[e0 + i][o0 + 4] = t1;
    }
    // re-init acc with inter_b1
    {
        float4 b1a = *(const float4*)&ib1[o0];
        float4 b1b = *(const float4*)&ib1[o0 + 4];
#pragma unroll
        for (int i = 0; i < 4; ++i) {
            acc[i][0] = b1a.x; acc[i][1] = b1a.y; acc[i][2] = b1a.z; acc[i][3] = b1a.w;
            acc[i][4] = b1b.x; acc[i][5] = b1b.y; acc[i][6] = b1b.z; acc[i][7] = b1b.w;
        }
    }
    __syncthreads();   // t visible

    // ---- GEMM2 (inter_w1) ----
    for (int kp = 0; kp < 8; ++kp) {
        const int k0 = kp * 16;
        __syncthreads();
#pragma unroll
        for (int j = 0; j < 8; ++j) {
            int n = ng * 8 + j;
            sW[kk][n] = iw1[(size_t)n * 128 + k0 + kk];
        }
        __syncthreads();
#pragma unroll
        for (int q = 0; q < 16; ++q) {
            const int k = k0 + q;
            float a[4];
            a[0] = sA[e0 + 0][k]; a[1] = sA[e0 + 1][k];
            a[2] = sA[e0 + 2][k]; a[3] = sA[e0 + 3][k];
            float4 wA = *(const float4*)&sW[q][o0];
            float4 wB = *(const float4*)&sW[q][o0 + 4];
#pragma unroll
            for (int i = 0; i < 4; ++i) {
                acc[i][0] += a[i] * wA.x; acc[i][1] += a[i] * wA.y;
                acc[i][2] += a[i] * wA.z; acc[i][3] += a[i] * wA.w;
                acc[i][4] += a[i] * wB.x; acc[i][5] += a[i] * wB.y;
                acc[i][6] += a[i] * wB.z; acc[i][7] += a[i] * wB.w;
            }
        }
    }

    // ---- inter epilogue: relu, dot inter_w2, reduce over tx ----
    {
        float4 w2a = *(const float4*)&iw2[o0];
        float4 w2b = *(const float4*)&iw2[o0 + 4];
        float ibias2 = ib2[0];
#pragma unroll
        for (int i = 0; i < 4; ++i) {
            float p = fmaxf(acc[i][0], 0.f) * w2a.x + fmaxf(acc[i][1], 0.f) * w2a.y
                    + fmaxf(acc[i][2], 0.f) * w2a.z + fmaxf(acc[i][3], 0.f) * w2a.w
                    + fmaxf(acc[i][4], 0.f) * w2b.x + fmaxf(acc[i][5], 0.f) * w2b.y
                    + fmaxf(acc[i][6], 0.f) * w2b.z + fmaxf(acc[i][7], 0.f) * w2b.w;
            p += __shfl_xor(p, 1);
            p += __shfl_xor(p, 2);
            p += __shfl_xor(p, 4);
            p += __shfl_xor(p, 8);
            if (tx == 0) sIS[e0 + i] = p + ibias2;
        }
    }
    __syncthreads();

    // ---- force + scatter ----
    if (tid < 64) {
        int e = tid;
        float w = sIS[e] * sG[e];
        float d = dist[eb + e];
        float coef = 5.f * w / ((d + 1e-6f) * (d + 5.f));
        const float* rv = &rel_vec[(size_t)(eb + e) * 3];
        int n = sEL[e];
        atomicAdd(&dp[n * 3 + 0], coef * rv[0]);
        atomicAdd(&dp[n * 3 + 1], coef * rv[1]);
        atomicAdd(&dp[n * 3 + 2], coef * rv[2]);
    }
}

// ---------------------------------------------------------------------------
// Build concat input for the scale MLP: Xc[n] = [h_node(128), ne(2), nrm, 0]
// ---------------------------------------------------------------------------
__global__ void build_xc(float* __restrict__ Xc, const float* __restrict__ h_node,
                         const float* __restrict__ ne, const float* __restrict__ dp)
{
    int idx = blockIdx.x * 256 + threadIdx.x;
    if (idx >= N_NODES * 33) return;
    int n = idx / 33, c = idx % 33;
    if (c < 32) {
        ((float4*)Xc)[(size_t)n * 33 + c] = ((const float4*)h_node)[(size_t)n * 32 + c];
    } else {
        float x = dp[n * 3], y = dp[n * 3 + 1], z = dp[n * 3 + 2];
        float nrm = sqrtf(x * x + y * y + z * z);
        float4 v;
        v.x = ne[n * 2]; v.y = ne[n * 2 + 1]; v.z = nrm; v.w = 0.f;
        ((float4*)Xc)[(size_t)n * 33 + 32] = v;
    }
}

// pad scale_w1 (128x131) to (128x132) with zero last col
__global__ void build_wc(float* __restrict__ Wc, const float* __restrict__ sw1)
{
    int idx = blockIdx.x * 256 + threadIdx.x;
    if (idx >= 128 * 132) return;
    int o = idx / 132, k = idx % 132;
    Wc[idx] = (k < 131) ? sw1[(size_t)o * 131 + k] : 0.f;
}

// out[n] = dp[n] * sigmoid(U[n] . scale_w2 + sb2)
__global__ __launch_bounds__(256)
void finalize(const float* __restrict__ U, const float* __restrict__ sw2,
              const float* __restrict__ sb2, const float* __restrict__ dp,
              float* __restrict__ out)
{
    int node = blockIdx.x * 4 + (threadIdx.x >> 6);
    int lane = threadIdx.x & 63;
    const float* u = &U[(size_t)node * 128];
    float p = u[lane] * sw2[lane] + u[lane + 64] * sw2[lane + 64];
    p += __shfl_xor(p, 1);
    p += __shfl_xor(p, 2);
    p += __shfl_xor(p, 4);
    p += __shfl_xor(p, 8);
    p += __shfl_xor(p, 16);
    p += __shfl_xor(p, 32);
    if (lane == 0) {
        float s = 1.f / (1.f + expf(-(p + sb2[0])));
        out[node * 3 + 0] = dp[node * 3 + 0] * s;
        out[node * 3 + 1] = dp[node * 3 + 1] * s;
        out[node * 3 + 2] = dp[node * 3 + 2] * s;
    }
}

extern "C" void kernel_launch(void* const* d_in, const int* in_sizes, int n_in,
                              void* d_out, int out_size, void* d_ws, size_t ws_size,
                              hipStream_t stream)
{
    const float* h_node  = (const float*)d_in[0];
    const float* h_edge  = (const float*)d_in[1];
    const int*   eidx    = (const int*)  d_in[2];
    const float* rel_vec = (const float*)d_in[3];
    const float* dist    = (const float*)d_in[4];
    const float* ne      = (const float*)d_in[5];
    const float* lw1 = (const float*)d_in[6];  const float* lb1 = (const float*)d_in[7];
    const float* lw2 = (const float*)d_in[8];  const float* lb2 = (const float*)d_in[9];
    const float* rw1 = (const float*)d_in[10]; const float* rb1 = (const float*)d_in[11];
    const float* rw2 = (const float*)d_in[12]; const float* rb2 = (const float*)d_in[13];
    const float* bond_w  = (const float*)d_in[14];
    const float* nodeb_w = (const float*)d_in[15];
    const float* iw1 = (const float*)d_in[16]; const float* ib1 = (const float*)d_in[17];
    const float* iw2 = (const float*)d_in[18]; const float* ib2 = (const float*)d_in[19];
    const float* gw1 = (const float*)d_in[20]; const float* gb1 = (const float*)d_in[21];
    const float* gw2 = (const float*)d_in[22]; const float* gb2 = (const float*)d_in[23];
    const float* sw1 = (const float*)d_in[24]; const float* sb1 = (const float*)d_in[25];
    const float* sw2 = (const float*)d_in[26]; const float* sb2 = (const float*)d_in[27];
    float* out = (float*)d_out;

    float* W = (float*)d_ws;
    const size_t NM = (size_t)N_NODES * 128;
    float* tmp = W;                                 // 6.4M floats (reused as U)
    float* LF  = W + NM;                            // 6.4M (reused as Xc, spills into RF)
    float* RF  = W + 2 * NM;                        // 6.4M
    float* Lp  = W + 3 * NM;                        // 6.4M
    float* Rp  = W + 4 * NM;                        // 6.4M
    float* GLX = W + 5 * NM;                        // 1.6M
    float* GR  = GLX + (size_t)N_NODES * 32;        // 1.6M
    float* dp  = GR + (size_t)N_NODES * 32;         // 150k
    float* Wc  = dp + (size_t)N_NODES * 3;          // 16896
    float* Xc  = LF;                                // reuse (LF/RF dead after edge kernel)
    float* U   = tmp;                               // reuse

    hipMemsetAsync(dp, 0, N_NODES * 3 * sizeof(float), stream);

    dim3 blk(256);
    dim3 g128((N_NODES + 63) / 64, 2);
    dim3 g32((N_NODES + 63) / 64, 1);

    // node precompute: MLPs on 50k nodes (not 800k edges), then project through
    // nodeb_lin_w and gate_w1 node-slices so the edge kernel only gathers.
    gemm_nt<true,  true ><<<g128, blk, 0, stream>>>(h_node, 128, lw1, 128, lb1, tmp, 128, N_NODES, 128, 128);
    gemm_nt<false, true ><<<g128, blk, 0, stream>>>(tmp, 128, lw2, 128, lb2, LF, 128, N_NODES, 128, 128);
    gemm_nt<true,  true ><<<g128, blk, 0, stream>>>(h_node, 128, rw1, 128, rb1, tmp, 128, N_NODES, 128, 128);
    gemm_nt<false, true ><<<g128, blk, 0, stream>>>(tmp, 128, rw2, 128, rb2, RF, 128, N_NODES, 128, 128);
    gemm_nt<false, false><<<g128, blk, 0, stream>>>(LF, 128, nodeb_w,       256, nullptr, Lp, 128, N_NODES, 128, 128);
    gemm_nt<false, false><<<g128, blk, 0, stream>>>(RF, 128, nodeb_w + 128, 256, nullptr, Rp, 128, N_NODES, 128, 128);
    gemm_nt<false, false><<<g32,  blk, 0, stream>>>(LF, 128, gw1 + 128, 386, nullptr, GLX, 32, N_NODES, 32, 128);
    gemm_nt<false, false><<<g32,  blk, 0, stream>>>(RF, 128, gw1 + 256, 386, nullptr, GR,  32, N_NODES, 32, 128);
    fix_glx<<<(N_NODES * 32 + 255) / 256, blk, 0, stream>>>(GLX, ne, gw1, gb1);

    edge_kernel<<<N_EDGES / 64, blk, 0, stream>>>(h_edge, eidx, rel_vec, dist, Lp, Rp, GLX, GR,
                                                  bond_w, iw1, ib1, iw2, ib2, gw1, gw2, gb2, dp);

    build_xc<<<(N_NODES * 33 + 255) / 256, blk, 0, stream>>>(Xc, h_node, ne, dp);
    build_wc<<<(128 * 132 + 255) / 256, blk, 0, stream>>>(Wc, sw1);
    gemm_nt<true, true><<<g128, blk, 0, stream>>>(Xc, 132, Wc, 132, sb1, U, 128, N_NODES, 128, 132);
    finalize<<<N_NODES / 4, blk, 0, stream>>>(U, sw2, sb2, dp, out);
}

// Round 3
// 833.909 us; speedup vs baseline: 2.2253x; 2.2253x over previous
//
#include <hip/hip_runtime.h>
#include <math.h>

#define N_NODES 50000
#define N_EDGES 800000

using bf16x8 = __attribute__((ext_vector_type(8))) short;
using f32x4  = __attribute__((ext_vector_type(4))) float;
typedef unsigned short u16;
typedef unsigned int   u32;

__device__ __forceinline__ u16 f2bf(float f) {
    union { float f; u32 u; } v; v.f = f;
    u32 u = v.u + 0x7fffu + ((v.u >> 16) & 1u);   // round-to-nearest-even
    return (u16)(u >> 16);
}
__device__ __forceinline__ float bf2f(u32 h) {
    union { u32 u; float f; } v; v.u = h << 16;
    return v.f;
}

#define SA_LD 136   // 64-edge A tile leading dim (bf16), 16B-aligned rows
#define SW_LD 40    // weight-panel leading dim

// ---------------------------------------------------------------------------
// Generic bf16 MFMA GEMM: C[MxN](bf16) = act(A[MxK](bf16) @ W[NxK](bf16)^T + bias)
// 64x64 tile, 256 threads (4 waves, wave w owns m-subtile w), K-step 32.
// ---------------------------------------------------------------------------
template<bool RELU>
__global__ __launch_bounds__(256, 4)
void mfma_gemm(const u16* __restrict__ A, int lda,
               const u16* __restrict__ W, int ldw,
               const float* __restrict__ bias,
               u16* __restrict__ C, int ldc,
               int M, int N, int K)
{
    __shared__ u16 sA[64 * SW_LD];
    __shared__ u16 sW[64 * SW_LD];
    const int tid = threadIdx.x;
    const int w = tid >> 6, lane = tid & 63, lx = lane & 15, quad = lane >> 4;
    const int m0 = blockIdx.x * 64, n0 = blockIdx.y * 64;

    f32x4 acc[4];
#pragma unroll
    for (int nt = 0; nt < 4; ++nt) {
        float b = bias ? bias[n0 + nt * 16 + lx] : 0.f;
        f32x4 t; t[0] = b; t[1] = b; t[2] = b; t[3] = b; acc[nt] = t;
    }

    const int sr = tid >> 2;            // 0..63 panel row
    const int sseg = (tid & 3) * 8;     // k-offset within panel (4 thr/row x 8 elems = 32)
    const int ksteps = K >> 5;
    for (int ks = 0; ks < ksteps; ++ks) {
        const int k0 = ks * 32;
        __syncthreads();
        int am = m0 + sr; if (am >= M) am = M - 1;
        uint4 va = *(const uint4*)&A[(size_t)am * lda + k0 + sseg];
        *(uint4*)&sA[sr * SW_LD + sseg] = va;
        uint4 vw = *(const uint4*)&W[(size_t)(n0 + sr) * ldw + k0 + sseg];
        *(uint4*)&sW[sr * SW_LD + sseg] = vw;
        __syncthreads();
        bf16x8 af = *(const bf16x8*)&sA[(w * 16 + lx) * SW_LD + quad * 8];
#pragma unroll
        for (int nt = 0; nt < 4; ++nt) {
            bf16x8 bf = *(const bf16x8*)&sW[(nt * 16 + lx) * SW_LD + quad * 8];
            acc[nt] = __builtin_amdgcn_mfma_f32_16x16x32_bf16(af, bf, acc[nt], 0, 0, 0);
        }
    }
#pragma unroll
    for (int r = 0; r < 4; ++r) {
        int m = m0 + w * 16 + quad * 4 + r;
        if (m >= M) continue;
#pragma unroll
        for (int nt = 0; nt < 4; ++nt) {
            float v = acc[nt][r];
            if (RELU) v = fmaxf(v, 0.f);
            C[(size_t)m * ldc + n0 + nt * 16 + lx] = f2bf(v);
        }
    }
}

// ---------------------------------------------------------------------------
// Convert h_node fp32 -> bf16 (float4-wide)
// ---------------------------------------------------------------------------
__global__ void conv_hnode(const float* __restrict__ src, u16* __restrict__ dst)
{
    int idx = blockIdx.x * 256 + threadIdx.x;       // one float4 per thread
    if (idx >= N_NODES * 32) return;
    float4 v = ((const float4*)src)[idx];
    uint2 o;
    o.x = (u32)f2bf(v.x) | ((u32)f2bf(v.y) << 16);
    o.y = (u32)f2bf(v.z) | ((u32)f2bf(v.w) << 16);
    *(uint2*)&dst[(size_t)idx * 4] = o;
}

// ---------------------------------------------------------------------------
// Small weight conversions, flat-indexed.
// ---------------------------------------------------------------------------
__global__ void prep_small(const float* lw1, const float* rw1,
                           const float* lb1, const float* rb1,
                           const float* bond_w, const float* iw1, const float* gw1,
                           const float* sw1,
                           u16* W1cat, float* b1cat, u16* bond_bf, u16* iw1_bf,
                           u16* gate_bf, u16* sw1c)
{
    int idx = blockIdx.x * 256 + threadIdx.x;
    if (idx < 32768) {
        int i = idx >> 7, k = idx & 127;
        float v = (i < 128) ? lw1[i * 128 + k] : rw1[(i - 128) * 128 + k];
        W1cat[idx] = f2bf(v);
    } else if (idx < 33024) {
        int i = idx - 32768;
        b1cat[i] = (i < 128) ? lb1[i] : rb1[i - 128];
    } else if (idx < 49408) {
        int t = idx - 33024;
        bond_bf[t] = f2bf(bond_w[t]);
    } else if (idx < 65792) {
        int t = idx - 49408;
        iw1_bf[t] = f2bf(iw1[t]);
    } else if (idx < 69888) {
        int t = idx - 65792;
        int g = t >> 7, k = t & 127;
        gate_bf[t] = f2bf(gw1[(size_t)g * 386 + k]);
    } else if (idx < 90368) {
        int t = idx - 69888;
        int o = t / 160, k = t % 160;
        sw1c[t] = (k < 131) ? f2bf(sw1[(size_t)o * 131 + k]) : (u16)0;
    }
}

// ---------------------------------------------------------------------------
// Compose projection weights (fold lw2/rw2 into nodeb_lin_w & gate_w1 node slices)
// WP[320][256] bf16, rows PERMUTED for vectorized edge-kernel gathers:
//   rows   0..127 : Lp  block, orig col c = (r&7)*16 + (r>>3), K 0..127 (L half)
//   rows 128..159 : GLX block, orig col g = (r&1)*16 + (r>>1), K 0..127
//   rows 160..287 : Rp  block, K 128..255 (R half)
//   rows 288..319 : GR  block, K 128..255
// bP[320] float = composed bias at the same permuted positions.
// ---------------------------------------------------------------------------
__global__ void compose_wp(const float* __restrict__ nodeb_w, const float* __restrict__ gw1,
                           const float* __restrict__ lw2, const float* __restrict__ rw2,
                           const float* __restrict__ lb2, const float* __restrict__ rb2,
                           const float* __restrict__ gb1,
                           u16* __restrict__ WP, float* __restrict__ bP)
{
    int idx = blockIdx.x * 256 + threadIdx.x;
    if (idx >= 320 * 256) return;
    int i = idx >> 8;      // permuted output row 0..319
    int j = idx & 255;     // K index 0..255
    bool leftRow = (i < 160);
    bool leftK = (j < 128);
    if (leftRow != leftK) { WP[idx] = 0; return; }

    const float* src;      // 128-length fp32 row to compose
    const float* w2 = leftRow ? lw2 : rw2;
    const float* b2 = leftRow ? lb2 : rb2;
    float biasExtra = 0.f;
    if (i < 128) {
        int c = ((i & 7) << 4) + (i >> 3);
        src = nodeb_w + (size_t)c * 256;
    } else if (i < 160) {
        int r = i - 128, g = ((r & 1) << 4) + (r >> 1);
        src = gw1 + (size_t)g * 386 + 128;
        biasExtra = gb1[g];
    } else if (i < 288) {
        int r = i - 160, c = ((r & 7) << 4) + (r >> 3);
        src = nodeb_w + (size_t)c * 256 + 128;
    } else {
        int r = i - 288, g = ((r & 1) << 4) + (r >> 1);
        src = gw1 + (size_t)g * 386 + 256;
    }
    int jj = j & 127;
    float s = 0.f;
#pragma unroll 4
    for (int k = 0; k < 128; ++k)
        s += src[k] * w2[(size_t)k * 128 + jj];
    WP[idx] = f2bf(s);
    if (jj == 0) {
        float b = biasExtra;
        for (int k = 0; k < 128; ++k) b += src[k] * b2[k];
        bP[i] = b;
    }
}

// ---------------------------------------------------------------------------
// Add node_extra part into GLX block of P (bf16 RMW). gb1 already in bP.
// P layout per node: [Lp(128 perm) | GLX(32 perm) | Rp(128 perm) | GR(32 perm)]
// ---------------------------------------------------------------------------
__global__ void fix_glx(u16* __restrict__ P, const float* __restrict__ ne,
                        const float* __restrict__ gw1)
{
    int idx = blockIdx.x * 256 + threadIdx.x;
    if (idx >= N_NODES * 32) return;
    int n = idx >> 5, g = idx & 31;                       // g = original gate channel
    int pos = ((g & 15) << 1) + (g >> 4);                 // perm32
    u16* p = &P[(size_t)n * 320 + 128 + pos];
    float v = bf2f(*p) + ne[n * 2] * gw1[(size_t)g * 386 + 384]
                       + ne[n * 2 + 1] * gw1[(size_t)g * 386 + 385];
    *p = f2bf(v);
}

// ---------------------------------------------------------------------------
// Fused edge kernel (MFMA): 64 edges/block, 256 threads (4 waves x 16 edges).
// ---------------------------------------------------------------------------
__global__ __launch_bounds__(256, 4)
void edge_kernel(const float* __restrict__ he,
                 const int*   __restrict__ eidx,
                 const float* __restrict__ rel_vec,
                 const float* __restrict__ dist,
                 const u16*   __restrict__ P,
                 const u16*   __restrict__ bondw,
                 const u16*   __restrict__ iw1w,
                 const u16*   __restrict__ gatew,
                 const float* __restrict__ ib1,
                 const float* __restrict__ iw2,
                 const float* __restrict__ ib2,
                 const float* __restrict__ gw2,
                 const float* __restrict__ gb2,
                 float* __restrict__ dp)
{
    __shared__ u16 sA[64 * SA_LD];
    __shared__ u16 sW[128 * SW_LD];
    __shared__ u16 sWg[32 * SW_LD];
    __shared__ int sEL[64], sER[64];
    __shared__ float sG[64], sIS[64];

    const int tid = threadIdx.x;
    const int w = tid >> 6, lane = tid & 63, lx = lane & 15, quad = lane >> 4;
    const int eb = blockIdx.x * 64;

    if (tid < 64) { sEL[tid] = eidx[eb + tid]; sER[tid] = eidx[N_EDGES + eb + tid]; }

    // stage h_edge tile -> bf16 LDS (complete: 8*256 iters x 4 elems = 8192)
#pragma unroll
    for (int j = 0; j < 8; ++j) {
        int fid = j * 256 + tid;
        int e = fid >> 5, kq = (fid & 31) << 2;
        float4 v = *(const float4*)&he[(size_t)(eb + e) * 128 + kq];
        uint2 o;
        o.x = (u32)f2bf(v.x) | ((u32)f2bf(v.y) << 16);
        o.y = (u32)f2bf(v.z) | ((u32)f2bf(v.w) << 16);
        *(uint2*)&sA[e * SA_LD + kq] = o;
    }

    f32x4 acc[8], accg[2];
#pragma unroll
    for (int i = 0; i < 8; ++i) { f32x4 z; z[0]=0;z[1]=0;z[2]=0;z[3]=0; acc[i] = z; }
    { f32x4 z; z[0]=0;z[1]=0;z[2]=0;z[3]=0; accg[0] = z; accg[1] = z; }

    // weight staging geometry: 128 rows, 2 threads/row, 16 elems (2 x uint4) each
    const int wrow = tid >> 1;
    const int wseg = (tid & 1) * 16;

    // ---- GEMM1 (bond) + fused gate ----
    for (int ks = 0; ks < 4; ++ks) {
        const int k0 = ks * 32;
        __syncthreads();
        {
            uint4 v0 = *(const uint4*)&bondw[wrow * 128 + k0 + wseg];
            uint4 v1 = *(const uint4*)&bondw[wrow * 128 + k0 + wseg + 8];
            *(uint4*)&sW[wrow * SW_LD + wseg] = v0;
            *(uint4*)&sW[wrow * SW_LD + wseg + 8] = v1;
            if (tid < 64) {      // 32 gate rows, 2 threads/row, 16 elems each
                uint4 g0 = *(const uint4*)&gatew[wrow * 128 + k0 + wseg];
                uint4 g1 = *(const uint4*)&gatew[wrow * 128 + k0 + wseg + 8];
                *(uint4*)&sWg[wrow * SW_LD + wseg] = g0;
                *(uint4*)&sWg[wrow * SW_LD + wseg + 8] = g1;
            }
        }
        __syncthreads();
        bf16x8 af = *(const bf16x8*)&sA[(w * 16 + lx) * SA_LD + k0 + quad * 8];
#pragma unroll
        for (int nt = 0; nt < 8; ++nt) {
            bf16x8 bf = *(const bf16x8*)&sW[(nt * 16 + lx) * SW_LD + quad * 8];
            acc[nt] = __builtin_amdgcn_mfma_f32_16x16x32_bf16(af, bf, acc[nt], 0, 0, 0);
        }
#pragma unroll
        for (int nt = 0; nt < 2; ++nt) {
            bf16x8 bf = *(const bf16x8*)&sWg[(nt * 16 + lx) * SW_LD + quad * 8];
            accg[nt] = __builtin_amdgcn_mfma_f32_16x16x32_bf16(af, bf, accg[nt], 0, 0, 0);
        }
    }

    // ---- gate epilogue ----
    {
        float gw2a = gw2[lx], gw2b = gw2[16 + lx];
        float gb2v = gb2[0];
#pragma unroll
        for (int r = 0; r < 4; ++r) {
            int erow = w * 16 + quad * 4 + r;
            size_t lbase = (size_t)sEL[erow] * 320;
            size_t rbase = (size_t)sER[erow] * 320 + 160;
            u32 gl = *(const u32*)&P[lbase + 128 + lx * 2];
            u32 gr = *(const u32*)&P[rbase + 128 + lx * 2];
            float g0 = bf2f(gl & 0xffff) + bf2f(gr & 0xffff);       // orig col lx
            float g1 = bf2f(gl >> 16) + bf2f(gr >> 16);             // orig col 16+lx
            float v = fmaxf(accg[0][r] + g0, 0.f) * gw2a
                    + fmaxf(accg[1][r] + g1, 0.f) * gw2b;
            v += __shfl_xor(v, 1); v += __shfl_xor(v, 2);
            v += __shfl_xor(v, 4); v += __shfl_xor(v, 8);
            if (lx == 0) sG[erow] = 1.f / (1.f + __expf(-(v + gb2v)));
        }
    }

    __syncthreads();   // all GEMM1 sA reads complete

    // ---- t-epilogue: t = acc + Lp[el] + Rp[er] -> sA (bf16) ----
#pragma unroll
    for (int r = 0; r < 4; ++r) {
        int erow = w * 16 + quad * 4 + r;
        size_t lbase = (size_t)sEL[erow] * 320;
        size_t rbase = (size_t)sER[erow] * 320 + 160;
        uint4 lv = *(const uint4*)&P[lbase + lx * 8];   // perm: 8 bf16 = cols {nt*16+lx}
        uint4 rv = *(const uint4*)&P[rbase + lx * 8];
        const u32* lw_ = (const u32*)&lv;
        const u32* rw_ = (const u32*)&rv;
#pragma unroll
        for (int nt = 0; nt < 8; ++nt) {
            u32 lh = (nt & 1) ? (lw_[nt >> 1] >> 16) : (lw_[nt >> 1] & 0xffff);
            u32 rh = (nt & 1) ? (rw_[nt >> 1] >> 16) : (rw_[nt >> 1] & 0xffff);
            float tv = acc[nt][r] + bf2f(lh) + bf2f(rh);
            sA[erow * SA_LD + nt * 16 + lx] = f2bf(tv);
        }
    }
    // re-init acc with inter_b1 (per output column)
#pragma unroll
    for (int nt = 0; nt < 8; ++nt) {
        float b = ib1[nt * 16 + lx];
        f32x4 t; t[0] = b; t[1] = b; t[2] = b; t[3] = b; acc[nt] = t;
    }
    __syncthreads();   // t visible to all waves

    // ---- GEMM2 (inter_w1) ----
    for (int ks = 0; ks < 4; ++ks) {
        const int k0 = ks * 32;
        __syncthreads();
        {
            uint4 v0 = *(const uint4*)&iw1w[wrow * 128 + k0 + wseg];
            uint4 v1 = *(const uint4*)&iw1w[wrow * 128 + k0 + wseg + 8];
            *(uint4*)&sW[wrow * SW_LD + wseg] = v0;
            *(uint4*)&sW[wrow * SW_LD + wseg + 8] = v1;
        }
        __syncthreads();
        bf16x8 af = *(const bf16x8*)&sA[(w * 16 + lx) * SA_LD + k0 + quad * 8];
#pragma unroll
        for (int nt = 0; nt < 8; ++nt) {
            bf16x8 bf = *(const bf16x8*)&sW[(nt * 16 + lx) * SW_LD + quad * 8];
            acc[nt] = __builtin_amdgcn_mfma_f32_16x16x32_bf16(af, bf, acc[nt], 0, 0, 0);
        }
    }

    // ---- inter epilogue: relu, dot iw2, lane-reduce ----
    {
        float ib2v = ib2[0];
        float iw2v[8];
#pragma unroll
        for (int nt = 0; nt < 8; ++nt) iw2v[nt] = iw2[nt * 16 + lx];
#pragma unroll
        for (int r = 0; r < 4; ++r) {
            float v = 0.f;
#pragma unroll
            for (int nt = 0; nt < 8; ++nt)
                v += fmaxf(acc[nt][r], 0.f) * iw2v[nt];
            v += __shfl_xor(v, 1); v += __shfl_xor(v, 2);
            v += __shfl_xor(v, 4); v += __shfl_xor(v, 8);
            if (lx == 0) sIS[w * 16 + quad * 4 + r] = v + ib2v;
        }
    }
    __syncthreads();

    // ---- force + scatter ----
    if (tid < 64) {
        float wgt = sIS[tid] * sG[tid];
        float d = dist[eb + tid];
        float coef = 5.f * wgt / ((d + 1e-6f) * (d + 5.f));
        const float* rv = &rel_vec[(size_t)(eb + tid) * 3];
        int n = sEL[tid];
        atomicAdd(&dp[n * 3 + 0], coef * rv[0]);
        atomicAdd(&dp[n * 3 + 1], coef * rv[1]);
        atomicAdd(&dp[n * 3 + 2], coef * rv[2]);
    }
}

// ---------------------------------------------------------------------------
// Build scale-MLP input Xc[50000][160] bf16 = [h_node(128), ne(2), nrm, zeros(29)]
// ---------------------------------------------------------------------------
__global__ void build_xc(u16* __restrict__ Xc, const float* __restrict__ h_node,
                         const float* __restrict__ ne, const float* __restrict__ dp)
{
    int idx = blockIdx.x * 256 + threadIdx.x;
    if (idx >= N_NODES * 160) return;
    int n = idx / 160, c = idx % 160;
    float v;
    if (c < 128) v = h_node[(size_t)n * 128 + c];
    else if (c == 128) v = ne[n * 2];
    else if (c == 129) v = ne[n * 2 + 1];
    else if (c == 130) {
        float x = dp[n * 3], y = dp[n * 3 + 1], z = dp[n * 3 + 2];
        v = sqrtf(x * x + y * y + z * z);
    } else v = 0.f;
    Xc[idx] = f2bf(v);
}

// ---------------------------------------------------------------------------
// out[n] = dp[n] * sigmoid(U[n] . scale_w2 + sb2)     (U bf16)
// ---------------------------------------------------------------------------
__global__ __launch_bounds__(256)
void finalize(const u16* __restrict__ U, const float* __restrict__ sw2,
              const float* __restrict__ sb2, const float* __restrict__ dp,
              float* __restrict__ out)
{
    int node = blockIdx.x * 4 + (threadIdx.x >> 6);
    int lane = threadIdx.x & 63;
    const u16* u = &U[(size_t)node * 128];
    float p = bf2f(u[lane]) * sw2[lane] + bf2f(u[lane + 64]) * sw2[lane + 64];
    p += __shfl_xor(p, 1);  p += __shfl_xor(p, 2);
    p += __shfl_xor(p, 4);  p += __shfl_xor(p, 8);
    p += __shfl_xor(p, 16); p += __shfl_xor(p, 32);
    if (lane == 0) {
        float s = 1.f / (1.f + __expf(-(p + sb2[0])));
        out[node * 3 + 0] = dp[node * 3 + 0] * s;
        out[node * 3 + 1] = dp[node * 3 + 1] * s;
        out[node * 3 + 2] = dp[node * 3 + 2] * s;
    }
}

extern "C" void kernel_launch(void* const* d_in, const int* in_sizes, int n_in,
                              void* d_out, int out_size, void* d_ws, size_t ws_size,
                              hipStream_t stream)
{
    const float* h_node  = (const float*)d_in[0];
    const float* h_edge  = (const float*)d_in[1];
    const int*   eidx    = (const int*)  d_in[2];
    const float* rel_vec = (const float*)d_in[3];
    const float* dist    = (const float*)d_in[4];
    const float* ne      = (const float*)d_in[5];
    const float* lw1 = (const float*)d_in[6];  const float* lb1 = (const float*)d_in[7];
    const float* lw2 = (const float*)d_in[8];  const float* lb2 = (const float*)d_in[9];
    const float* rw1 = (const float*)d_in[10]; const float* rb1 = (const float*)d_in[11];
    const float* rw2 = (const float*)d_in[12]; const float* rb2 = (const float*)d_in[13];
    const float* bond_w  = (const float*)d_in[14];
    const float* nodeb_w = (const float*)d_in[15];
    const float* iw1 = (const float*)d_in[16]; const float* ib1 = (const float*)d_in[17];
    const float* iw2 = (const float*)d_in[18]; const float* ib2 = (const float*)d_in[19];
    const float* gw1 = (const float*)d_in[20]; const float* gb1 = (const float*)d_in[21];
    const float* gw2 = (const float*)d_in[22]; const float* gb2 = (const float*)d_in[23];
    const float* sw1 = (const float*)d_in[24]; const float* sb1 = (const float*)d_in[25];
    const float* sw2 = (const float*)d_in[26]; const float* sb2 = (const float*)d_in[27];
    float* out = (float*)d_out;

    // ---- workspace carve (256B-aligned) ----
    char* base = (char*)d_ws;
    auto carve = [&](size_t bytes) { char* p = base; base += (bytes + 255) & ~(size_t)255; return p; };
    u16*  hnode_bf = (u16*) carve((size_t)N_NODES * 128 * 2);
    u16*  H1       = (u16*) carve((size_t)N_NODES * 256 * 2);
    u16*  P        = (u16*) carve((size_t)N_NODES * 320 * 2);
    u16*  Xc       = (u16*) carve((size_t)N_NODES * 160 * 2);
    u16*  U        = (u16*) carve((size_t)N_NODES * 128 * 2);
    u16*  W1cat    = (u16*) carve(256 * 128 * 2);
    u16*  WP       = (u16*) carve(320 * 256 * 2);
    u16*  bond_bf  = (u16*) carve(128 * 128 * 2);
    u16*  iw1_bf   = (u16*) carve(128 * 128 * 2);
    u16*  gate_bf  = (u16*) carve(32 * 128 * 2);
    u16*  sw1c     = (u16*) carve(128 * 160 * 2);
    float* b1cat   = (float*)carve(256 * 4);
    float* bP      = (float*)carve(320 * 4);
    float* dp      = (float*)carve((size_t)N_NODES * 3 * 4);

    hipMemsetAsync(dp, 0, (size_t)N_NODES * 3 * 4, stream);

    dim3 blk(256);
    conv_hnode<<<(N_NODES * 32 + 255) / 256, blk, 0, stream>>>(h_node, hnode_bf);
    prep_small<<<(90368 + 255) / 256, blk, 0, stream>>>(lw1, rw1, lb1, rb1, bond_w, iw1, gw1, sw1,
                                                        W1cat, b1cat, bond_bf, iw1_bf, gate_bf, sw1c);
    compose_wp<<<320, blk, 0, stream>>>(nodeb_w, gw1, lw2, rw2, lb2, rb2, gb1, WP, bP);

    const int MB = (N_NODES + 63) / 64;   // 782
    // H1 = relu(hnode @ [lw1;rw1]^T + [lb1;rb1])            [50000 x 256]
    mfma_gemm<true ><<<dim3(MB, 4), blk, 0, stream>>>(hnode_bf, 128, W1cat, 128, b1cat, H1, 256, N_NODES, 256, 128);
    // P = H1 @ WP^T + bP                                     [50000 x 320]  (Lp|GLX|Rp|GR, permuted)
    mfma_gemm<false><<<dim3(MB, 5), blk, 0, stream>>>(H1, 256, WP, 256, bP, P, 320, N_NODES, 320, 256);
    fix_glx<<<(N_NODES * 32 + 255) / 256, blk, 0, stream>>>(P, ne, gw1);

    edge_kernel<<<N_EDGES / 64, blk, 0, stream>>>(h_edge, eidx, rel_vec, dist, P,
                                                  bond_bf, iw1_bf, gate_bf,
                                                  ib1, iw2, ib2, gw2, gb2, dp);

    build_xc<<<(N_NODES * 160 + 255) / 256, blk, 0, stream>>>(Xc, h_node, ne, dp);
    // U = relu(Xc @ sw1c^T + sb1)                            [50000 x 128]
    mfma_gemm<true ><<<dim3(MB, 2), blk, 0, stream>>>(Xc, 160, sw1c, 160, sb1, U, 128, N_NODES, 128, 160);
    finalize<<<N_NODES / 4, blk, 0, stream>>>(U, sw2, sb2, dp, out);
}